// Round 1
// 975.926 us; speedup vs baseline: 1.0040x; 1.0040x over previous
//
#include <hip/hip_runtime.h>

#define HID 128
#define NNODE 50000
#define NEDGE 640000

typedef __attribute__((ext_vector_type(8))) short bf16x8;
typedef __attribute__((ext_vector_type(4))) float f32x4;

// ---------------------------------------------------------------- embed: x = emb[z]
static __global__ void embed_kernel(const int* __restrict__ z,
                                    const float* __restrict__ emb,
                                    float* __restrict__ x) {
  int i = blockIdx.x * 256 + threadIdx.x;
  const int total = NNODE * (HID / 4);
  if (i >= total) return;
  int node = i >> 5;
  int c = i & 31;
  ((float4*)x)[i] = ((const float4*)emb)[(size_t)z[node] * 32 + c];
}

// ---------------------------------------------------------------- CSR build
static __global__ void hist_kernel(const int* __restrict__ dst, int* __restrict__ deg) {
  int i = blockIdx.x * 256 + threadIdx.x;
  if (i < NEDGE) atomicAdd(&deg[dst[i]], 1);
}

static __global__ void scan_kernel(const int* __restrict__ deg,
                                   int* __restrict__ row_ptr,
                                   int* __restrict__ cursor) {
  __shared__ int sums[1024];
  int t = threadIdx.x;
  const int per = (NNODE + 1023) / 1024;
  int base = t * per;
  int s = 0;
  for (int i = 0; i < per; ++i) {
    int idx = base + i;
    if (idx < NNODE) s += deg[idx];
  }
  sums[t] = s;
  __syncthreads();
  for (int off = 1; off < 1024; off <<= 1) {
    int v = (t >= off) ? sums[t - off] : 0;
    __syncthreads();
    if (t >= off) sums[t] += v;
    __syncthreads();
  }
  int run = (t == 0) ? 0 : sums[t - 1];
  for (int i = 0; i < per; ++i) {
    int idx = base + i;
    if (idx < NNODE) {
      row_ptr[idx] = run;
      cursor[idx] = run;
      run += deg[idx];
    }
  }
  if (t == 1023) row_ptr[NNODE] = run;
}

static __global__ void fill_kernel(const int* __restrict__ src, const int* __restrict__ dst,
                                   int* __restrict__ cursor, int2* __restrict__ elist) {
  int i = blockIdx.x * 256 + threadIdx.x;
  if (i < NEDGE) {
    int d = dst[i];
    int p = atomicAdd(&cursor[d], 1);
    elist[p] = make_int2(i, src[i]);
  }
}

// ---------------------------------------------------------------- W split (once/call):
// Wt[hi|lo][c*2+g][n][136 k] bf16 (transposed so B-frag reads 8 consecutive k)
static __global__ void wsplit_kernel(const float* __restrict__ W1, const float* __restrict__ W2,
                                     unsigned short* __restrict__ whi,
                                     unsigned short* __restrict__ wlo) {
  int idx = blockIdx.x * 256 + threadIdx.x;
  if (idx >= 6 * 16384) return;
  int cg = idx >> 14;            // c*2+g
  int rem = idx & 16383;
  int k = rem >> 7, n = rem & 127;
  int c = cg >> 1, g = cg & 1;
  float v = (g ? W2 : W1)[c * 16384 + k * 128 + n];
  unsigned u = __float_as_uint(v);
  unsigned hb = u >> 16;                             // truncate -> lo captures residue
  float hf = __uint_as_float(hb << 16);
  unsigned lb = __float_as_uint(v - hf) >> 16;
  int o = cg * 17408 + n * 136 + k;                  // 17408 = 128*136
  whi[o] = (unsigned short)hb;
  wlo[o] = (unsigned short)lb;
}

// ---------------------------------------------------------------- gather:
// out[n] = x[n] + sum_{e->n} relu(x[src]+ea[e])
// ONE NODE PER HALF-WAVE: 32 lanes x float4 cover the 128-float row.
// Per wave: 2 independent CSR streams (halves), main loop unrolled x4
// -> 8 edges (8KB) in flight. Store is a contiguous 1KB wave store.
static __global__ __launch_bounds__(256) void gather_kernel(
    const float* __restrict__ x, const float* __restrict__ ea,
    const int* __restrict__ row_ptr, const int2* __restrict__ elist,
    float* __restrict__ out) {
  const int tid = threadIdx.x;
  const int wave = tid >> 6;
  const int lane = tid & 63;
  const int half = lane >> 5;
  const int li = lane & 31;
  const int node = blockIdx.x * 8 + wave * 2 + half;   // node owned by this half-wave
  const f32x4* x4 = (const f32x4*)x;
  const f32x4* e4 = (const f32x4*)ea;

  f32x4 a0 = (f32x4){0.f, 0.f, 0.f, 0.f};
  f32x4 a1 = (f32x4){0.f, 0.f, 0.f, 0.f};
  f32x4 a2 = (f32x4){0.f, 0.f, 0.f, 0.f};
  f32x4 a3 = (f32x4){0.f, 0.f, 0.f, 0.f};
  int j = 0, je = 0;
  if (node < NNODE) {
    j = row_ptr[node];
    je = row_ptr[node + 1];
    a0 = x4[(size_t)node * 32 + li];                  // residual init
  }
  // main: 4 edges per half-wave per iteration (independent chains)
  for (; j + 4 <= je; j += 4) {
    int2 e0 = elist[j];
    int2 e1 = elist[j + 1];
    int2 e2 = elist[j + 2];
    int2 e3 = elist[j + 3];
    f32x4 xv0 = x4[(size_t)e0.y * 32 + li];
    f32x4 ev0 = __builtin_nontemporal_load(&e4[(size_t)e0.x * 32 + li]);
    f32x4 xv1 = x4[(size_t)e1.y * 32 + li];
    f32x4 ev1 = __builtin_nontemporal_load(&e4[(size_t)e1.x * 32 + li]);
    f32x4 xv2 = x4[(size_t)e2.y * 32 + li];
    f32x4 ev2 = __builtin_nontemporal_load(&e4[(size_t)e2.x * 32 + li]);
    f32x4 xv3 = x4[(size_t)e3.y * 32 + li];
    f32x4 ev3 = __builtin_nontemporal_load(&e4[(size_t)e3.x * 32 + li]);
#pragma unroll
    for (int q = 0; q < 4; ++q) {
      a0[q] += fmaxf(xv0[q] + ev0[q], 0.f);
      a1[q] += fmaxf(xv1[q] + ev1[q], 0.f);
      a2[q] += fmaxf(xv2[q] + ev2[q], 0.f);
      a3[q] += fmaxf(xv3[q] + ev3[q], 0.f);
    }
  }
  if (j + 2 <= je) {                                   // 2-edge tail step
    int2 e0 = elist[j];
    int2 e1 = elist[j + 1];
    f32x4 xv0 = x4[(size_t)e0.y * 32 + li];
    f32x4 ev0 = __builtin_nontemporal_load(&e4[(size_t)e0.x * 32 + li]);
    f32x4 xv1 = x4[(size_t)e1.y * 32 + li];
    f32x4 ev1 = __builtin_nontemporal_load(&e4[(size_t)e1.x * 32 + li]);
#pragma unroll
    for (int q = 0; q < 4; ++q) {
      a0[q] += fmaxf(xv0[q] + ev0[q], 0.f);
      a1[q] += fmaxf(xv1[q] + ev1[q], 0.f);
    }
    j += 2;
  }
  if (j < je) {                                        // 1-edge tail step
    int2 e0 = elist[j];
    f32x4 xv0 = x4[(size_t)e0.y * 32 + li];
    f32x4 ev0 = __builtin_nontemporal_load(&e4[(size_t)e0.x * 32 + li]);
#pragma unroll
    for (int q = 0; q < 4; ++q) a0[q] += fmaxf(xv0[q] + ev0[q], 0.f);
  }
  if (node < NNODE) {
#pragma unroll
    for (int q = 0; q < 4; ++q) a0[q] += a1[q] + a2[q] + a3[q];
    ((f32x4*)out)[(size_t)node * 32 + li] = a0;        // both halves -> 1KB/wave
  }
}

// ---------------------------------------------------------------- MFMA MLP:
// xout = x + [relu?](relu(in@W1+b1)@W2+b2), bf16 hi/lo split (3 mfma/product).
// 64 rows/block, wave w owns rows w*16..+15 x all 128 cols (8 16x16 tiles).
// LDS: W chunk hi/lo 36.9K + t fp32 33.8K = 70.7K -> 2 blocks/CU.
static __global__ __launch_bounds__(256) void mlp_mfma(
    const float* __restrict__ in, const float* __restrict__ xres,
    const unsigned short* __restrict__ wt1hi, const unsigned short* __restrict__ wt1lo,
    const unsigned short* __restrict__ wt2hi, const unsigned short* __restrict__ wt2lo,
    const float* __restrict__ b1, const float* __restrict__ b2,
    float* __restrict__ xout, int relu_out) {
  __shared__ unsigned short WbHi[128 * 72];          // [n][72] k-chunk of 64
  __shared__ unsigned short WbLo[128 * 72];
  __shared__ float Ts[64 * 132];                     // t, fp32, ld=132
  const int tid = threadIdx.x;
  const int w = tid >> 6, l = tid & 63;
  const int lm = l & 15, quad = l >> 4;
  const int row0 = blockIdx.x * 64;

  float b1v[8], b2v[8];
#pragma unroll
  for (int t = 0; t < 8; ++t) { b1v[t] = b1[t * 16 + lm]; b2v[t] = b2[t * 16 + lm]; }

  f32x4 acc[8];
#pragma unroll
  for (int t = 0; t < 8; ++t) acc[t] = (f32x4){0.f, 0.f, 0.f, 0.f};

  // A row for frag loads (clamped; tail stores are guarded)
  int arow = row0 + w * 16 + lm;
  if (arow >= NNODE) arow = NNODE - 1;

  // ---- GEMM 1: acc = in @ W1  (A from global, split on the fly)
  for (int kc = 0; kc < 128; kc += 64) {
    __syncthreads();
    for (int idx = tid; idx < 128 * 8; idx += 256) {
      int n = idx >> 3, seg = idx & 7;
      *(uint4*)&WbHi[n * 72 + seg * 8] = *(const uint4*)&wt1hi[n * 136 + kc + seg * 8];
      *(uint4*)&WbLo[n * 72 + seg * 8] = *(const uint4*)&wt1lo[n * 136 + kc + seg * 8];
    }
    __syncthreads();
#pragma unroll
    for (int ks = 0; ks < 64; ks += 32) {
      const float* ap = in + (size_t)arow * 128 + kc + ks + quad * 8;
      float4 av0 = *(const float4*)ap;
      float4 av1 = *(const float4*)(ap + 4);
      float av[8] = {av0.x, av0.y, av0.z, av0.w, av1.x, av1.y, av1.z, av1.w};
      bf16x8 ah, al;
#pragma unroll
      for (int jj = 0; jj < 8; ++jj) {
        unsigned u = __float_as_uint(av[jj]);
        unsigned hb = u >> 16;
        float hf = __uint_as_float(hb << 16);
        unsigned lb = __float_as_uint(av[jj] - hf) >> 16;
        ah[jj] = (short)hb; al[jj] = (short)lb;
      }
#pragma unroll
      for (int t = 0; t < 8; ++t) {
        int off = (t * 16 + lm) * 72 + ks + quad * 8;
        bf16x8 bh = *(const bf16x8*)&WbHi[off];
        bf16x8 bl = *(const bf16x8*)&WbLo[off];
        acc[t] = __builtin_amdgcn_mfma_f32_16x16x32_bf16(ah, bh, acc[t], 0, 0, 0);
        acc[t] = __builtin_amdgcn_mfma_f32_16x16x32_bf16(ah, bl, acc[t], 0, 0, 0);
        acc[t] = __builtin_amdgcn_mfma_f32_16x16x32_bf16(al, bh, acc[t], 0, 0, 0);
      }
    }
  }
  __syncthreads();

  // t = relu(acc + b1) -> Ts ; C layout: row = w*16 + quad*4 + r, col = t*16+lm
#pragma unroll
  for (int t = 0; t < 8; ++t)
#pragma unroll
    for (int r = 0; r < 4; ++r)
      Ts[(w * 16 + quad * 4 + r) * 132 + t * 16 + lm] = fmaxf(acc[t][r] + b1v[t], 0.f);

#pragma unroll
  for (int t = 0; t < 8; ++t) acc[t] = (f32x4){0.f, 0.f, 0.f, 0.f};
  __syncthreads();

  // ---- GEMM 2: acc = t @ W2  (A from Ts fp32, split on the fly)
  for (int kc = 0; kc < 128; kc += 64) {
    __syncthreads();
    for (int idx = tid; idx < 128 * 8; idx += 256) {
      int n = idx >> 3, seg = idx & 7;
      *(uint4*)&WbHi[n * 72 + seg * 8] = *(const uint4*)&wt2hi[n * 136 + kc + seg * 8];
      *(uint4*)&WbLo[n * 72 + seg * 8] = *(const uint4*)&wt2lo[n * 136 + kc + seg * 8];
    }
    __syncthreads();
#pragma unroll
    for (int ks = 0; ks < 64; ks += 32) {
      const float* tp = &Ts[(w * 16 + lm) * 132 + kc + ks + quad * 8];
      float4 av0 = *(const float4*)tp;
      float4 av1 = *(const float4*)(tp + 4);
      float av[8] = {av0.x, av0.y, av0.z, av0.w, av1.x, av1.y, av1.z, av1.w};
      bf16x8 ah, al;
#pragma unroll
      for (int jj = 0; jj < 8; ++jj) {
        unsigned u = __float_as_uint(av[jj]);
        unsigned hb = u >> 16;
        float hf = __uint_as_float(hb << 16);
        unsigned lb = __float_as_uint(av[jj] - hf) >> 16;
        ah[jj] = (short)hb; al[jj] = (short)lb;
      }
#pragma unroll
      for (int t = 0; t < 8; ++t) {
        int off = (t * 16 + lm) * 72 + ks + quad * 8;
        bf16x8 bh = *(const bf16x8*)&WbHi[off];
        bf16x8 bl = *(const bf16x8*)&WbLo[off];
        acc[t] = __builtin_amdgcn_mfma_f32_16x16x32_bf16(ah, bh, acc[t], 0, 0, 0);
        acc[t] = __builtin_amdgcn_mfma_f32_16x16x32_bf16(ah, bl, acc[t], 0, 0, 0);
        acc[t] = __builtin_amdgcn_mfma_f32_16x16x32_bf16(al, bh, acc[t], 0, 0, 0);
      }
    }
  }

  // epilogue: bias, optional relu, residual, store (scalar but coalesced 4-row x 16-col)
#pragma unroll
  for (int t = 0; t < 8; ++t) {
#pragma unroll
    for (int r = 0; r < 4; ++r) {
      int row = row0 + w * 16 + quad * 4 + r;
      if (row < NNODE) {
        int col = t * 16 + lm;
        float v = acc[t][r] + b2v[t];
        if (relu_out) v = fmaxf(v, 0.f);
        v += xres[(size_t)row * 128 + col];
        xout[(size_t)row * 128 + col] = v;
      }
    }
  }
}

extern "C" void kernel_launch(void* const* d_in, const int* in_sizes, int n_in,
                              void* d_out, int out_size, void* d_ws, size_t ws_size,
                              hipStream_t stream) {
  const int*   z   = (const int*)d_in[0];
  const int*   ei  = (const int*)d_in[1];
  const float* ea  = (const float*)d_in[2];
  const float* emb = (const float*)d_in[3];
  const float* W1  = (const float*)d_in[4];
  const float* b1  = (const float*)d_in[5];
  const float* W2  = (const float*)d_in[6];
  const float* b2  = (const float*)d_in[7];
  float* outp = (float*)d_out;

  char* ws = (char*)d_ws;
  float* xbuf   = (float*)(ws + 0);
  float* obuf   = (float*)(ws + 25600000);
  int*   deg    = (int*)  (ws + 51200000);
  int*   cursor = (int*)  (ws + 51400000);
  int*   rowptr = (int*)  (ws + 51600000);
  int2*  elist  = (int2*) (ws + 51800016);
  unsigned short* whi = (unsigned short*)(ws + 57000000);  // 6*17408*2 B = 208,896
  unsigned short* wlo = (unsigned short*)(ws + 57250000);

  const int* srcv = ei;
  const int* dstv = ei + NEDGE;

  hipMemsetAsync(deg, 0, NNODE * sizeof(int), stream);
  embed_kernel<<<(NNODE * 32 + 255) / 256, 256, 0, stream>>>(z, emb, xbuf);
  hist_kernel<<<(NEDGE + 255) / 256, 256, 0, stream>>>(dstv, deg);
  scan_kernel<<<1, 1024, 0, stream>>>(deg, rowptr, cursor);
  fill_kernel<<<(NEDGE + 255) / 256, 256, 0, stream>>>(srcv, dstv, cursor, elist);
  wsplit_kernel<<<(6 * 16384 + 255) / 256, 256, 0, stream>>>(W1, W2, whi, wlo);

  for (int i = 0; i < 3; ++i) {
    gather_kernel<<<(NNODE + 7) / 8, 256, 0, stream>>>(xbuf, ea, rowptr, elist, obuf);
    float* xo = (i == 2) ? outp : xbuf;
    mlp_mfma<<<(NNODE + 63) / 64, 256, 0, stream>>>(
        obuf, xbuf,
        whi + (size_t)(i * 2 + 0) * 17408, wlo + (size_t)(i * 2 + 0) * 17408,
        whi + (size_t)(i * 2 + 1) * 17408, wlo + (size_t)(i * 2 + 1) * 17408,
        b1 + (size_t)i * HID, b2 + (size_t)i * HID,
        xo, (i < 2) ? 1 : 0);
  }
}

// Round 2
// 938.236 us; speedup vs baseline: 1.0443x; 1.0402x over previous
//
#include <hip/hip_runtime.h>

#define HID 128
#define NNODE 50000
#define NEDGE 640000

typedef __attribute__((ext_vector_type(8))) short bf16x8;
typedef __attribute__((ext_vector_type(4))) float f32x4;

// ---------------------------------------------------------------- embed: x = emb[z]
static __global__ void embed_kernel(const int* __restrict__ z,
                                    const float* __restrict__ emb,
                                    float* __restrict__ x) {
  int i = blockIdx.x * 256 + threadIdx.x;
  const int total = NNODE * (HID / 4);
  if (i >= total) return;
  int node = i >> 5;
  int c = i & 31;
  ((float4*)x)[i] = ((const float4*)emb)[(size_t)z[node] * 32 + c];
}

// ---------------------------------------------------------------- CSR build
static __global__ void hist_kernel(const int* __restrict__ dst, int* __restrict__ deg) {
  int i = blockIdx.x * 256 + threadIdx.x;
  if (i < NEDGE) atomicAdd(&deg[dst[i]], 1);
}

// single block, 1024 threads; int4-vectorized both passes (52 = 13 int4 per thread)
static __global__ void scan_kernel(const int* __restrict__ deg,
                                   int* __restrict__ row_ptr,
                                   int* __restrict__ cursor) {
  __shared__ int sums[1024];
  int t = threadIdx.x;
  const int per = 52;                       // 52*1024 = 53248 >= NNODE; 208B base stride (16B-aligned)
  int base = t * per;
  int s = 0;
  if (base + per <= NNODE) {
#pragma unroll
    for (int i = 0; i < per; i += 4) {
      int4 v = *(const int4*)&deg[base + i];
      s += v.x + v.y + v.z + v.w;
    }
  } else {
    for (int i = 0; i < per; ++i) {
      int idx = base + i;
      if (idx < NNODE) s += deg[idx];
    }
  }
  sums[t] = s;
  __syncthreads();
  for (int off = 1; off < 1024; off <<= 1) {
    int v = (t >= off) ? sums[t - off] : 0;
    __syncthreads();
    if (t >= off) sums[t] += v;
    __syncthreads();
  }
  int run = (t == 0) ? 0 : sums[t - 1];
  if (base + per <= NNODE) {
#pragma unroll
    for (int i = 0; i < per; i += 4) {
      int4 v = *(const int4*)&deg[base + i];
      int4 rp;
      rp.x = run; run += v.x;
      rp.y = run; run += v.y;
      rp.z = run; run += v.z;
      rp.w = run; run += v.w;
      *(int4*)&row_ptr[base + i] = rp;
      *(int4*)&cursor[base + i] = rp;
    }
  } else {
    for (int i = 0; i < per; ++i) {
      int idx = base + i;
      if (idx < NNODE) { row_ptr[idx] = run; cursor[idx] = run; run += deg[idx]; }
    }
  }
  if (t == 1023) row_ptr[NNODE] = sums[1023];
}

static __global__ void fill_kernel(const int* __restrict__ src, const int* __restrict__ dst,
                                   int* __restrict__ cursor, int2* __restrict__ elist) {
  int i = blockIdx.x * 256 + threadIdx.x;
  if (i < NEDGE) {
    int d = dst[i];
    int p = atomicAdd(&cursor[d], 1);
    elist[p] = make_int2(i, src[i]);
  }
}

// ---------------------------------------------------------------- W split (once/call):
// Wt[hi|lo][c*2+g][n][136 k] bf16 (transposed so B-frag reads 8 consecutive k)
static __global__ void wsplit_kernel(const float* __restrict__ W1, const float* __restrict__ W2,
                                     unsigned short* __restrict__ whi,
                                     unsigned short* __restrict__ wlo) {
  int idx = blockIdx.x * 256 + threadIdx.x;
  if (idx >= 6 * 16384) return;
  int cg = idx >> 14;            // c*2+g
  int rem = idx & 16383;
  int k = rem >> 7, n = rem & 127;
  int c = cg >> 1, g = cg & 1;
  float v = (g ? W2 : W1)[c * 16384 + k * 128 + n];
  unsigned u = __float_as_uint(v);
  unsigned hb = u >> 16;                             // truncate -> lo captures residue
  float hf = __uint_as_float(hb << 16);
  unsigned lb = __float_as_uint(v - hf) >> 16;
  int o = cg * 17408 + n * 136 + k;                  // 17408 = 128*136
  whi[o] = (unsigned short)hb;
  wlo[o] = (unsigned short)lb;
}

// ---------------------------------------------------------------- fused conv:
// Per block of 64 nodes:
//   phase G: gather agg+x into Ts (LDS)      [was gather_kernel -> obuf]
//   GEMM1:   acc = Ts @ W1 (hi/lo split)     [A from LDS]
//   t = relu(acc+b1) -> Ts
//   GEMM2:   acc = Ts @ W2
//   epilogue: +b2, optional relu, + x residual, store xout
// LDS: W chunk hi/lo 36.9K + Ts fp32 33.8K = 70.7K -> 2 blocks/CU; phase-diverse
// blocks overlap (one gathers while the other does MFMA).
static __global__ __launch_bounds__(256) void conv_fused(
    const float* __restrict__ x, const float* __restrict__ ea,
    const int* __restrict__ row_ptr, const int2* __restrict__ elist,
    const unsigned short* __restrict__ wt1hi, const unsigned short* __restrict__ wt1lo,
    const unsigned short* __restrict__ wt2hi, const unsigned short* __restrict__ wt2lo,
    const float* __restrict__ b1, const float* __restrict__ b2,
    float* __restrict__ xout, int relu_out) {
  __shared__ unsigned short WbHi[128 * 72];          // [n][72] k-chunk of 64
  __shared__ unsigned short WbLo[128 * 72];
  __shared__ float Ts[64 * 132];                     // gather rows, then t rows; ld=132
  const int tid = threadIdx.x;
  const int w = tid >> 6, l = tid & 63;
  const int lm = l & 15, quad = l >> 4;
  const int hw = tid >> 5;                           // half-wave id 0..7
  const int li = tid & 31;
  const int row0 = blockIdx.x * 64;

#define STAGE(HP, LP, KC)                                                        \
  for (int idx = tid; idx < 128 * 8; idx += 256) {                               \
    int n_ = idx >> 3, seg_ = idx & 7;                                           \
    *(uint4*)&WbHi[n_ * 72 + seg_ * 8] = *(const uint4*)&HP[n_ * 136 + (KC) + seg_ * 8]; \
    *(uint4*)&WbLo[n_ * 72 + seg_ * 8] = *(const uint4*)&LP[n_ * 136 + (KC) + seg_ * 8]; \
  }

  // stage W1 chunk0 up front (overlaps with gather; visible after the gather barrier)
  STAGE(wt1hi, wt1lo, 0)

  // ---- phase G: gather. one node per half-wave, 8 nodes per half-wave total.
  {
    const f32x4* x4 = (const f32x4*)x;
    const f32x4* e4 = (const f32x4*)ea;
    for (int nl = hw; nl < 64; nl += 8) {
      int node = row0 + nl;
      f32x4 a0 = (f32x4){0.f, 0.f, 0.f, 0.f};
      f32x4 a1 = a0, a2 = a0, a3 = a0;
      int j = 0, je = 0;
      if (node < NNODE) {
        j = row_ptr[node];
        je = row_ptr[node + 1];
        a0 = x4[(size_t)node * 32 + li];             // residual-in-A (out = agg + x)
      }
      for (; j + 4 <= je; j += 4) {
        int2 e0 = elist[j];
        int2 e1 = elist[j + 1];
        int2 e2 = elist[j + 2];
        int2 e3 = elist[j + 3];
        f32x4 xv0 = x4[(size_t)e0.y * 32 + li];
        f32x4 ev0 = __builtin_nontemporal_load(&e4[(size_t)e0.x * 32 + li]);
        f32x4 xv1 = x4[(size_t)e1.y * 32 + li];
        f32x4 ev1 = __builtin_nontemporal_load(&e4[(size_t)e1.x * 32 + li]);
        f32x4 xv2 = x4[(size_t)e2.y * 32 + li];
        f32x4 ev2 = __builtin_nontemporal_load(&e4[(size_t)e2.x * 32 + li]);
        f32x4 xv3 = x4[(size_t)e3.y * 32 + li];
        f32x4 ev3 = __builtin_nontemporal_load(&e4[(size_t)e3.x * 32 + li]);
#pragma unroll
        for (int q = 0; q < 4; ++q) {
          a0[q] += fmaxf(xv0[q] + ev0[q], 0.f);
          a1[q] += fmaxf(xv1[q] + ev1[q], 0.f);
          a2[q] += fmaxf(xv2[q] + ev2[q], 0.f);
          a3[q] += fmaxf(xv3[q] + ev3[q], 0.f);
        }
      }
      if (j + 2 <= je) {
        int2 e0 = elist[j];
        int2 e1 = elist[j + 1];
        f32x4 xv0 = x4[(size_t)e0.y * 32 + li];
        f32x4 ev0 = __builtin_nontemporal_load(&e4[(size_t)e0.x * 32 + li]);
        f32x4 xv1 = x4[(size_t)e1.y * 32 + li];
        f32x4 ev1 = __builtin_nontemporal_load(&e4[(size_t)e1.x * 32 + li]);
#pragma unroll
        for (int q = 0; q < 4; ++q) {
          a0[q] += fmaxf(xv0[q] + ev0[q], 0.f);
          a1[q] += fmaxf(xv1[q] + ev1[q], 0.f);
        }
        j += 2;
      }
      if (j < je) {
        int2 e0 = elist[j];
        f32x4 xv0 = x4[(size_t)e0.y * 32 + li];
        f32x4 ev0 = __builtin_nontemporal_load(&e4[(size_t)e0.x * 32 + li]);
#pragma unroll
        for (int q = 0; q < 4; ++q) a0[q] += fmaxf(xv0[q] + ev0[q], 0.f);
      }
#pragma unroll
      for (int q = 0; q < 4; ++q) a0[q] += a1[q] + a2[q] + a3[q];
      *(f32x4*)&Ts[nl * 132 + li * 4] = a0;          // zeros for invalid rows
    }
  }

  float b1v[8], b2v[8];
#pragma unroll
  for (int t = 0; t < 8; ++t) { b1v[t] = b1[t * 16 + lm]; b2v[t] = b2[t * 16 + lm]; }

  f32x4 acc[8];
#pragma unroll
  for (int t = 0; t < 8; ++t) acc[t] = (f32x4){0.f, 0.f, 0.f, 0.f};

  __syncthreads();                                   // Ts + W1 chunk0 ready

  // A-frag loader from Ts (fp32 -> bf16 hi/lo split on the fly)
#define GEMM_CHUNK(KC)                                                           \
  _Pragma("unroll")                                                              \
  for (int ks = 0; ks < 64; ks += 32) {                                          \
    const float* tp = &Ts[(w * 16 + lm) * 132 + (KC) + ks + quad * 8];           \
    float4 av0 = *(const float4*)tp;                                             \
    float4 av1 = *(const float4*)(tp + 4);                                       \
    float av[8] = {av0.x, av0.y, av0.z, av0.w, av1.x, av1.y, av1.z, av1.w};      \
    bf16x8 ah, al;                                                               \
    _Pragma("unroll")                                                            \
    for (int jj = 0; jj < 8; ++jj) {                                             \
      unsigned u = __float_as_uint(av[jj]);                                      \
      unsigned hb = u >> 16;                                                     \
      float hf = __uint_as_float(hb << 16);                                      \
      unsigned lb = __float_as_uint(av[jj] - hf) >> 16;                          \
      ah[jj] = (short)hb; al[jj] = (short)lb;                                    \
    }                                                                            \
    _Pragma("unroll")                                                            \
    for (int t = 0; t < 8; ++t) {                                                \
      int off = (t * 16 + lm) * 72 + ks + quad * 8;                              \
      bf16x8 bh = *(const bf16x8*)&WbHi[off];                                    \
      bf16x8 bl = *(const bf16x8*)&WbLo[off];                                    \
      acc[t] = __builtin_amdgcn_mfma_f32_16x16x32_bf16(ah, bh, acc[t], 0, 0, 0); \
      acc[t] = __builtin_amdgcn_mfma_f32_16x16x32_bf16(ah, bl, acc[t], 0, 0, 0); \
      acc[t] = __builtin_amdgcn_mfma_f32_16x16x32_bf16(al, bh, acc[t], 0, 0, 0); \
    }                                                                            \
  }

  // ---- GEMM 1: acc = Ts @ W1
  GEMM_CHUNK(0)
  __syncthreads();
  STAGE(wt1hi, wt1lo, 64)
  __syncthreads();
  GEMM_CHUNK(64)
  __syncthreads();

  // t = relu(acc + b1) -> Ts ; C layout: row = w*16 + quad*4 + r, col = t*16+lm
#pragma unroll
  for (int t = 0; t < 8; ++t)
#pragma unroll
    for (int r = 0; r < 4; ++r)
      Ts[(w * 16 + quad * 4 + r) * 132 + t * 16 + lm] = fmaxf(acc[t][r] + b1v[t], 0.f);

#pragma unroll
  for (int t = 0; t < 8; ++t) acc[t] = (f32x4){0.f, 0.f, 0.f, 0.f};
  __syncthreads();

  // ---- GEMM 2: acc = Ts @ W2
  STAGE(wt2hi, wt2lo, 0)
  __syncthreads();
  GEMM_CHUNK(0)
  __syncthreads();
  STAGE(wt2hi, wt2lo, 64)
  __syncthreads();
  GEMM_CHUNK(64)

  // epilogue: bias, optional relu, residual, store
#pragma unroll
  for (int t = 0; t < 8; ++t) {
#pragma unroll
    for (int r = 0; r < 4; ++r) {
      int row = row0 + w * 16 + quad * 4 + r;
      if (row < NNODE) {
        int col = t * 16 + lm;
        float v = acc[t][r] + b2v[t];
        if (relu_out) v = fmaxf(v, 0.f);
        v += x[(size_t)row * 128 + col];
        xout[(size_t)row * 128 + col] = v;
      }
    }
  }
#undef STAGE
#undef GEMM_CHUNK
}

extern "C" void kernel_launch(void* const* d_in, const int* in_sizes, int n_in,
                              void* d_out, int out_size, void* d_ws, size_t ws_size,
                              hipStream_t stream) {
  const int*   z   = (const int*)d_in[0];
  const int*   ei  = (const int*)d_in[1];
  const float* ea  = (const float*)d_in[2];
  const float* emb = (const float*)d_in[3];
  const float* W1  = (const float*)d_in[4];
  const float* b1  = (const float*)d_in[5];
  const float* W2  = (const float*)d_in[6];
  const float* b2  = (const float*)d_in[7];
  float* outp = (float*)d_out;

  char* ws = (char*)d_ws;
  float* xbuf   = (float*)(ws + 0);
  float* obuf   = (float*)(ws + 25600000);           // ping-pong partner of xbuf
  int*   deg    = (int*)  (ws + 51200000);
  int*   cursor = (int*)  (ws + 51400000);
  int*   rowptr = (int*)  (ws + 51600000);
  int2*  elist  = (int2*) (ws + 51800016);
  unsigned short* whi = (unsigned short*)(ws + 57000000);  // 6*17408*2 B = 208,896
  unsigned short* wlo = (unsigned short*)(ws + 57250000);

  const int* srcv = ei;
  const int* dstv = ei + NEDGE;

  hipMemsetAsync(deg, 0, NNODE * sizeof(int), stream);
  embed_kernel<<<(NNODE * 32 + 255) / 256, 256, 0, stream>>>(z, emb, xbuf);
  hist_kernel<<<(NEDGE + 255) / 256, 256, 0, stream>>>(dstv, deg);
  scan_kernel<<<1, 1024, 0, stream>>>(deg, rowptr, cursor);
  fill_kernel<<<(NEDGE + 255) / 256, 256, 0, stream>>>(srcv, dstv, cursor, elist);
  wsplit_kernel<<<(6 * 16384 + 255) / 256, 256, 0, stream>>>(W1, W2, whi, wlo);

  // ping-pong: xbuf -> obuf -> xbuf -> out (gather reads arbitrary rows of the
  // input buffer, so in-place update would race)
  const float* xin = xbuf;
  for (int i = 0; i < 3; ++i) {
    float* xo = (i == 2) ? outp : ((i == 0) ? obuf : xbuf);
    conv_fused<<<(NNODE + 63) / 64, 256, 0, stream>>>(
        xin, ea, rowptr, elist,
        whi + (size_t)(i * 2 + 0) * 17408, wlo + (size_t)(i * 2 + 0) * 17408,
        whi + (size_t)(i * 2 + 1) * 17408, wlo + (size_t)(i * 2 + 1) * 17408,
        b1 + (size_t)i * HID, b2 + (size_t)i * HID,
        xo, (i < 2) ? 1 : 0);
    xin = xo;
  }
}